// Round 2
// baseline (2333.770 us; speedup 1.0000x reference)
//
#include <hip/hip_runtime.h>
#include <hip/hip_bf16.h>
#include <math.h>

#define N_NODES 60000
#define E_EDGES 200000
#define DIM     128
#define NINPK   256
#define TSTEPS  6
#define LLAYERS 2
#define BGRAPH  16

typedef float f32x4 __attribute__((ext_vector_type(4)));
typedef short s16x8 __attribute__((ext_vector_type(8)));

static __device__ __forceinline__ float sigm(float x) { return 1.f / (1.f + expf(-x)); }

// round-to-nearest-even float -> bf16 bits
static __device__ __forceinline__ short f2bf(float f) {
  unsigned u = __float_as_uint(f);
  u += 0x7FFFu + ((u >> 16) & 1u);
  return (short)(u >> 16);
}

// order-preserving float <-> uint for atomicMax-based segment max
static __device__ __forceinline__ unsigned fenc(float f) {
  unsigned u = __float_as_uint(f);
  return (u & 0x80000000u) ? ~u : (u | 0x80000000u);
}
static __device__ __forceinline__ float fdec(unsigned u) {
  u = (u & 0x80000000u) ? (u & 0x7fffffffu) : ~u;
  return __uint_as_float(u);
}

// ---------------- init: hx=gcn_weights, cx=0, meta=0, keys=0 ----------------
__global__ void k_init(const float* __restrict__ gcn, float* __restrict__ hx,
                       float* __restrict__ cx, int* __restrict__ meta,
                       unsigned* __restrict__ keys) {
  int i = blockIdx.x * blockDim.x + threadIdx.x;
  if (i < LLAYERS * DIM * DIM) { hx[i] = gcn[i]; cx[i] = 0.f; }
  if (i < BGRAPH * DIM) keys[i] = 0u;
  if (i < 32) meta[i] = 0;
}

// ---------------- edge bucketing by timestep ----------------
// meta layout: [0..5]=cnt  [8..13]=first  [16..22]=offsets (incl. total) [24..29]=cursor
__global__ void k_count(const int* __restrict__ et, int* __restrict__ meta) {
  __shared__ int loc[TSTEPS];
  if (threadIdx.x < TSTEPS) loc[threadIdx.x] = 0;
  __syncthreads();
  int e = blockIdx.x * blockDim.x + threadIdx.x;
  if (e < E_EDGES) atomicAdd(&loc[et[e]], 1);
  __syncthreads();
  if (threadIdx.x < TSTEPS && loc[threadIdx.x]) atomicAdd(&meta[threadIdx.x], loc[threadIdx.x]);
}

__global__ void k_scan(int* __restrict__ meta) {
  if (blockIdx.x == 0 && threadIdx.x == 0) {
    int off = 0, f = 0;
    for (int t = 0; t < TSTEPS; ++t) {
      meta[16 + t] = off; off += meta[t];
      meta[8 + t] = f; f |= (meta[t] > 0);
    }
    meta[16 + TSTEPS] = off;
  }
}

__global__ void k_fill(const int* __restrict__ et, int* __restrict__ meta,
                       int* __restrict__ eord) {
  int e = blockIdx.x * blockDim.x + threadIdx.x;
  if (e >= E_EDGES) return;
  int t = et[e];
  int pos = atomicAdd(&meta[24 + t], 1);
  eord[meta[16 + t] + pos] = e;
}

// ---------------- zero float4 region ----------------
__global__ void k_zero(float4* __restrict__ p, long n4) {
  long i = (long)blockIdx.x * blockDim.x + threadIdx.x;
  if (i < n4) p[i] = make_float4(0.f, 0.f, 0.f, 0.f);
}

// ---------------- touched flags for time-t edges (bucketed) ----------------
__global__ void k_touch(const int* __restrict__ src, const int* __restrict__ dst,
                        const int* __restrict__ eord, const int* __restrict__ meta,
                        int* __restrict__ touched, int t) {
  int lo = meta[16 + t], n = meta[17 + t] - meta[16 + t];
  for (int i = blockIdx.x * blockDim.x + threadIdx.x; i < n;
       i += gridDim.x * blockDim.x) {
    int e = eord[lo + i];
    touched[src[e]] = 1;
    touched[dst[e]] = 1;
  }
}

// ---------------- LSTM part 1: g0 = x@Wih^T + b, g1 = x@(Wih+Whh)^T + b ----------------
__global__ void k_lstm_g(const float* __restrict__ hx, const float* __restrict__ Wih,
                         const float* __restrict__ Whh, const float* __restrict__ bih,
                         const float* __restrict__ bhh, float* __restrict__ g0,
                         float* __restrict__ g1) {
  int i = blockIdx.x >> 9;          // layer
  int c = blockIdx.x & 511;         // gate column 0..511
  int r = threadIdx.x;              // 0..127
  __shared__ float wi[DIM], wh[DIM];
  wi[r] = Wih[((long)i * 4 * DIM + c) * DIM + r];
  wh[r] = Whh[((long)i * 4 * DIM + c) * DIM + r];
  __syncthreads();
  const float* x = hx + ((long)i * DIM + r) * DIM;
  float a = 0.f, b = 0.f;
#pragma unroll 8
  for (int k = 0; k < DIM; ++k) {
    a = fmaf(x[k], wi[k], a);
    b = fmaf(x[k], wh[k], b);
  }
  float base = bih[i * 4 * DIM + c] + bhh[i * 4 * DIM + c];
  long o = ((long)i * 4 * DIM + c) * DIM + r;
  g0[o] = a + base;
  g1[o] = a + b + base;
}

// ---------------- LSTM part 2: gate nonlinearities + select ----------------
__global__ void k_lstm_upd(float* __restrict__ hx, float* __restrict__ cx,
                           const float* __restrict__ g0, const float* __restrict__ g1,
                           const int* __restrict__ meta, int t) {
  int idx = blockIdx.x * blockDim.x + threadIdx.x;
  if (idx >= LLAYERS * DIM * DIM) return;
  int i = idx >> 14;
  int rem = idx & 16383;
  int r = rem >> 7, j = rem & 127;
  long gb = (long)i * 4 * DIM * DIM;
  float gi0 = g0[gb + (0 * DIM + j) * DIM + r];
  float gg0 = g0[gb + (2 * DIM + j) * DIM + r];
  float go0 = g0[gb + (3 * DIM + j) * DIM + r];
  float gi1 = g1[gb + (0 * DIM + j) * DIM + r];
  float gf1 = g1[gb + (1 * DIM + j) * DIM + r];
  float gg1 = g1[gb + (2 * DIM + j) * DIM + r];
  float go1 = g1[gb + (3 * DIM + j) * DIM + r];
  float c_zero = sigm(gi0) * tanhf(gg0);
  float h_zero = sigm(go0) * tanhf(c_zero);
  float c0v = cx[idx];
  float c_st = sigm(gf1) * c0v + sigm(gi1) * tanhf(gg1);
  float h_st = sigm(go1) * tanhf(c_st);
  int first = meta[8 + t];
  int has = meta[t] > 0;
  float hold = hx[idx];
  float hi_v = first ? h_st : h_zero;
  float ci_v = first ? c0v : c_zero;
  hx[idx] = has ? hi_v : hold;
  cx[idx] = has ? ci_v : c0v;
}

// ---------------- weight prep: fp32 [K][128] -> bf16 [kb][c][g-swizzled][8] ----------------
__global__ void k_prep(const float* __restrict__ W, short* __restrict__ Wt, int K) {
  int idx = blockIdx.x * blockDim.x + threadIdx.x;
  int total = (K >> 6) * DIM * 8;
  if (idx >= total) return;
  int g = idx & 7;
  int c = (idx >> 3) & 127;
  int kb = idx >> 10;
  s16x8 s;
#pragma unroll
  for (int j = 0; j < 8; ++j) s[j] = f2bf(W[(long)(kb * 64 + g * 8 + j) * DIM + c]);
  *(s16x8*)&Wt[(((long)kb * DIM + c) * 8 + (g ^ (c & 7))) * 8] = s;
}

// ---------------- edge scatter (bucketed): S[dst] += w * H[src] ----------------
__global__ void k_scatter(const int* __restrict__ src, const int* __restrict__ dst,
                          const int* __restrict__ eord, const int* __restrict__ meta,
                          const float* __restrict__ ew, const float* __restrict__ H,
                          float* __restrict__ S, int t) {
  int lo = meta[16 + t];
  long n32 = (long)(meta[17 + t] - lo) << 5;
  for (long idx = (long)blockIdx.x * blockDim.x + threadIdx.x; idx < n32;
       idx += (long)gridDim.x * blockDim.x) {
    int i = (int)(idx >> 5);
    int e = eord[lo + i];
    int d = ((int)idx & 31) << 2;
    float w = ew[e];
    const float4 hv = *reinterpret_cast<const float4*>(H + (long)src[e] * DIM + d);
    float* o = S + (long)dst[e] * DIM + d;
    atomicAdd(o + 0, hv.x * w);
    atomicAdd(o + 1, hv.y * w);
    atomicAdd(o + 2, hv.z * w);
    atomicAdd(o + 3, hv.w * w);
  }
}

// ---------------- MFMA GEMM: C[n][c] = act(sum_k A[row(n)][k] * W[k][c] (+bias)) ----
// block = 256 thr (4 waves), tile = 128 rows x 128 cols, K staged in 64-chunks.
// LDS granule = 8 bf16 (16B); XOR swizzle granule ^= (row&7) kills bank conflicts.
template <int KTILES, bool GATHER, bool RELU, bool BIAS>
__global__ __launch_bounds__(256) void k_gemm_mfma(const float* __restrict__ A,
                                                   const int* __restrict__ rowids,
                                                   const short* __restrict__ Wt,
                                                   const float* __restrict__ bias,
                                                   float* __restrict__ C, int N) {
  __shared__ short As[128 * 64];
  __shared__ short Ws[128 * 64];
  __shared__ int rid[128];
  const int tid = threadIdx.x;
  const int n0 = blockIdx.x * 128;
  if (GATHER) {
    if (tid < 128) {
      int n = n0 + tid;
      rid[tid] = (n < N) ? rowids[n] * (KTILES * 64) : 0;
    }
  }
  const int lane = tid & 63;
  const int w = tid >> 6;
  f32x4 acc[2][8] = {};
  for (int kt = 0; kt < KTILES; ++kt) {
    __syncthreads();  // rid ready (kt=0) / previous compute done
    // stage A tile: 128 rows x 64 k, fp32 -> bf16, swizzled
#pragma unroll
    for (int p = 0; p < 4; ++p) {
      int gi = p * 256 + tid;
      int row = gi >> 3, g = gi & 7;
      int n = n0 + row;
      float4 v0 = make_float4(0.f, 0.f, 0.f, 0.f), v1 = v0;
      if (n < N) {
        long base = GATHER ? (long)rid[row] : (long)n * (KTILES * 64);
        const float* ap = A + base + kt * 64 + g * 8;
        v0 = *reinterpret_cast<const float4*>(ap);
        v1 = *reinterpret_cast<const float4*>(ap + 4);
      }
      s16x8 s;
      s[0] = f2bf(v0.x); s[1] = f2bf(v0.y); s[2] = f2bf(v0.z); s[3] = f2bf(v0.w);
      s[4] = f2bf(v1.x); s[5] = f2bf(v1.y); s[6] = f2bf(v1.z); s[7] = f2bf(v1.w);
      *(s16x8*)&As[(row * 8 + (g ^ (row & 7))) * 8] = s;
    }
    // stage W chunk: pre-swizzled bf16, linear 16KB copy
    const int4* wg = reinterpret_cast<const int4*>(Wt + kt * 128 * 64);
    int4* wl = reinterpret_cast<int4*>(Ws);
#pragma unroll
    for (int p = 0; p < 4; ++p) wl[p * 256 + tid] = wg[p * 256 + tid];
    __syncthreads();
    // compute: 2 k-steps of 32, 2 row-frags x 8 col-frags
#pragma unroll
    for (int kk = 0; kk < 2; ++kk) {
      int gb = kk * 4 + (lane >> 4);
      s16x8 a[2];
#pragma unroll
      for (int fr = 0; fr < 2; ++fr) {
        int row = w * 32 + fr * 16 + (lane & 15);
        a[fr] = *(const s16x8*)&As[(row * 8 + (gb ^ (row & 7))) * 8];
      }
#pragma unroll
      for (int fc = 0; fc < 8; ++fc) {
        int col = fc * 16 + (lane & 15);
        s16x8 b = *(const s16x8*)&Ws[(col * 8 + (gb ^ (col & 7))) * 8];
        acc[0][fc] = __builtin_amdgcn_mfma_f32_16x16x32_bf16(a[0], b, acc[0][fc], 0, 0, 0);
        acc[1][fc] = __builtin_amdgcn_mfma_f32_16x16x32_bf16(a[1], b, acc[1][fc], 0, 0, 0);
      }
    }
  }
  // epilogue: C/D layout col=lane&15, row=(lane>>4)*4+reg  [m89-verified]
  const int cb = lane & 15;
  const int rb = w * 32 + (lane >> 4) * 4;
#pragma unroll
  for (int fr = 0; fr < 2; ++fr) {
#pragma unroll
    for (int reg = 0; reg < 4; ++reg) {
      int n = n0 + rb + fr * 16 + reg;
      if (n >= N) continue;
      float* cp = C + (long)n * DIM;
#pragma unroll
      for (int fc = 0; fc < 8; ++fc) {
        float x = acc[fr][fc][reg];
        if (BIAS) x += bias[fc * 16 + cb];
        if (RELU) x = fmaxf(x, 0.f);
        cp[fc * 16 + cb] = x;
      }
    }
  }
}

// ---------------- write back touched rows: h[n] = ht[n] ----------------
__global__ void k_writeback(float* __restrict__ h, const float* __restrict__ ht,
                            const int* __restrict__ touched) {
  int idx = blockIdx.x * blockDim.x + threadIdx.x;
  int n = idx >> 5;
  if (n >= N_NODES) return;
  if (!touched[n]) return;
  int d = (idx & 31) << 2;
  *reinterpret_cast<float4*>(h + (long)n * DIM + d) =
      *reinterpret_cast<const float4*>(ht + (long)n * DIM + d);
}

// ---------------- segment max (graph_id sorted) ----------------
__global__ void k_segmax(const float* __restrict__ h, const int* __restrict__ gid,
                         unsigned* __restrict__ keys) {
  int d = threadIdx.x;  // 0..127
  int n0 = blockIdx.x * 64;
  int end = min(n0 + 64, N_NODES);
  if (n0 >= N_NODES) return;
  int curg = gid[n0];
  float m = -INFINITY;
  for (int n = n0; n < end; ++n) {
    int g = gid[n];
    if (g != curg) {
      atomicMax(&keys[(long)curg * DIM + d], fenc(m));
      curg = g;
      m = -INFINITY;
    }
    m = fmaxf(m, h[(long)n * DIM + d]);
  }
  atomicMax(&keys[(long)curg * DIM + d], fenc(m));
}

// ---------------- final: logits, probs, BCE loss ----------------
__global__ void k_final(const unsigned* __restrict__ keys, const float* __restrict__ outW,
                        const float* __restrict__ outB, const float* __restrict__ y,
                        float* __restrict__ out) {
  __shared__ float lt[BGRAPH];
  int tid = threadIdx.x;  // 64 threads: 4 per graph
  int b = tid >> 2, l4 = tid & 3;
  float s = 0.f;
  for (int d = l4; d < DIM; d += 4) {
    float v = fdec(keys[(long)b * DIM + d]);
    if (!isfinite(v)) v = 0.f;
    s += v * outW[d];
  }
  s += __shfl_down(s, 1);
  s += __shfl_down(s, 2);
  if (l4 == 0) {
    float l = s + outB[0];
    out[1 + b] = 1.f / (1.f + expf(-l));
    lt[b] = fmaxf(l, 0.f) - l * y[b] + log1pf(expf(-fabsf(l)));
  }
  __syncthreads();
  if (tid == 0) {
    float acc = 0.f;
    for (int i = 0; i < BGRAPH; ++i) acc += lt[i];
    out[0] = acc / (float)BGRAPH;
  }
}

extern "C" void kernel_launch(void* const* d_in, const int* in_sizes, int n_in,
                              void* d_out, int out_size, void* d_ws, size_t ws_size,
                              hipStream_t stream) {
  const int* word_ids = (const int*)d_in[0];
  const int* src = (const int*)d_in[1];
  const int* dst = (const int*)d_in[2];
  const int* et = (const int*)d_in[3];
  const float* ew = (const float*)d_in[4];
  const int* gid = (const int*)d_in[5];
  const float* y = (const float*)d_in[6];
  const float* wemb = (const float*)d_in[7];
  const float* adW = (const float*)d_in[8];
  const float* adb = (const float*)d_in[9];
  const float* gcn = (const float*)d_in[10];
  const float* Wih = (const float*)d_in[11];
  const float* Whh = (const float*)d_in[12];
  const float* bih = (const float*)d_in[13];
  const float* bhh = (const float*)d_in[14];
  const float* outW = (const float*)d_in[15];
  const float* outB = (const float*)d_in[16];
  float* out = (float*)d_out;

  char* ws = (char*)d_ws;
  const long ND = (long)N_NODES * DIM;  // 7,680,000 floats
  float* h = (float*)ws;        ws += ND * 4;
  float* tA = (float*)ws;       ws += ND * 4;
  float* S = (float*)ws;        ws += ND * 4;
  int* touched = (int*)ws;      ws += (long)N_NODES * 4;  // contiguous after S
  float* hx = (float*)ws;       ws += LLAYERS * DIM * DIM * 4;
  float* cx = (float*)ws;       ws += LLAYERS * DIM * DIM * 4;
  float* g0 = (float*)ws;       ws += LLAYERS * 4 * DIM * DIM * 4;
  float* g1 = (float*)ws;       ws += LLAYERS * 4 * DIM * DIM * 4;
  int* meta = (int*)ws;         ws += 32 * 4;
  unsigned* keys = (unsigned*)ws; ws += BGRAPH * DIM * 4;
  int* eord = (int*)ws;         ws += (long)E_EDGES * 4;
  short* WtAd = (short*)ws;     ws += 4L * DIM * 64 * 2;   // 256-K adapt, 64KB
  short* WtL0 = (short*)ws;     ws += 2L * DIM * 64 * 2;   // 32KB
  short* WtL1 = (short*)ws;     ws += 2L * DIM * 64 * 2;   // 32KB

  const long n4_S = ND / 4;
  const long n4_S_touch = (ND * 4 + (long)N_NODES * 4) / 16;
  const int gemm_blocks = (N_NODES + 127) / 128;

  k_init<<<128, 256, 0, stream>>>(gcn, hx, cx, meta, keys);
  k_count<<<(E_EDGES + 255) / 256, 256, 0, stream>>>(et, meta);
  k_scan<<<1, 64, 0, stream>>>(meta);
  k_fill<<<(E_EDGES + 255) / 256, 256, 0, stream>>>(et, meta, eord);
  k_prep<<<16, 256, 0, stream>>>(adW, WtAd, NINPK);

  // h0 = word_embeds[word_ids] @ adapt_W + adapt_b
  k_gemm_mfma<4, true, false, true><<<gemm_blocks, 256, 0, stream>>>(
      wemb, word_ids, WtAd, adb, h, N_NODES);

  for (int t = 0; t < TSTEPS; ++t) {
    k_zero<<<(int)((n4_S_touch + 255) / 256), 256, 0, stream>>>((float4*)S, n4_S_touch);
    k_touch<<<1024, 256, 0, stream>>>(src, dst, eord, meta, touched, t);
    // LSTM weight evolution
    k_lstm_g<<<LLAYERS * 512, 128, 0, stream>>>(hx, Wih, Whh, bih, bhh, g0, g1);
    k_lstm_upd<<<128, 256, 0, stream>>>(hx, cx, g0, g1, meta, t);
    k_prep<<<8, 256, 0, stream>>>(hx, WtL0, DIM);
    k_prep<<<8, 256, 0, stream>>>(hx + DIM * DIM, WtL1, DIM);
    // GCN layer 0
    k_scatter<<<4096, 256, 0, stream>>>(src, dst, eord, meta, ew, h, S, t);
    k_gemm_mfma<2, false, true, false><<<gemm_blocks, 256, 0, stream>>>(
        S, nullptr, WtL0, nullptr, tA, N_NODES);
    // GCN layer 1
    k_zero<<<(int)((n4_S + 255) / 256), 256, 0, stream>>>((float4*)S, n4_S);
    k_scatter<<<4096, 256, 0, stream>>>(src, dst, eord, meta, ew, tA, S, t);
    k_gemm_mfma<2, false, true, false><<<gemm_blocks, 256, 0, stream>>>(
        S, nullptr, WtL1, nullptr, tA, N_NODES);
    // write back touched rows
    k_writeback<<<N_NODES * 32 / 256, 256, 0, stream>>>(h, tA, touched);
  }

  k_segmax<<<(N_NODES + 63) / 64, 128, 0, stream>>>(h, gid, keys);
  k_final<<<1, 64, 0, stream>>>(keys, outW, outB, y, out);
}

// Round 3
// 1222.865 us; speedup vs baseline: 1.9084x; 1.9084x over previous
//
#include <hip/hip_runtime.h>
#include <hip/hip_bf16.h>
#include <math.h>

#define N_NODES 60000
#define E_EDGES 200000
#define DIM     128
#define NINPK   256
#define TSTEPS  6
#define LLAYERS 2
#define BGRAPH  16

typedef float f32x4 __attribute__((ext_vector_type(4)));
typedef short s16x8 __attribute__((ext_vector_type(8)));

static __device__ __forceinline__ float sigm(float x) { return 1.f / (1.f + expf(-x)); }

// round-to-nearest-even float -> bf16 bits
static __device__ __forceinline__ short f2bf(float f) {
  unsigned u = __float_as_uint(f);
  u += 0x7FFFu + ((u >> 16) & 1u);
  return (short)(u >> 16);
}

// order-preserving float <-> uint for atomicMax-based segment max
static __device__ __forceinline__ unsigned fenc(float f) {
  unsigned u = __float_as_uint(f);
  return (u & 0x80000000u) ? ~u : (u | 0x80000000u);
}
static __device__ __forceinline__ float fdec(unsigned u) {
  u = (u & 0x80000000u) ? (u & 0x7fffffffu) : ~u;
  return __uint_as_float(u);
}

// ---------------- init: hx=gcn_weights, cx=0, meta=0, keys=0 ----------------
__global__ void k_init(const float* __restrict__ gcn, float* __restrict__ hx,
                       float* __restrict__ cx, int* __restrict__ meta,
                       unsigned* __restrict__ keys) {
  int i = blockIdx.x * blockDim.x + threadIdx.x;
  if (i < LLAYERS * DIM * DIM) { hx[i] = gcn[i]; cx[i] = 0.f; }
  if (i < BGRAPH * DIM) keys[i] = 0u;
  if (i < 32) meta[i] = 0;
}

// ---------------- edge bucketing by timestep ----------------
// meta layout: [0..5]=cnt  [8..13]=first  [16..22]=offsets (incl. total) [24..29]=cursor
__global__ void k_count(const int* __restrict__ et, int* __restrict__ meta) {
  __shared__ int loc[TSTEPS];
  if (threadIdx.x < TSTEPS) loc[threadIdx.x] = 0;
  __syncthreads();
  int e = blockIdx.x * blockDim.x + threadIdx.x;
  if (e < E_EDGES) atomicAdd(&loc[et[e]], 1);
  __syncthreads();
  if (threadIdx.x < TSTEPS && loc[threadIdx.x]) atomicAdd(&meta[threadIdx.x], loc[threadIdx.x]);
}

__global__ void k_scan(int* __restrict__ meta) {
  if (blockIdx.x == 0 && threadIdx.x == 0) {
    int off = 0, f = 0;
    for (int t = 0; t < TSTEPS; ++t) {
      meta[16 + t] = off; off += meta[t];
      meta[8 + t] = f; f |= (meta[t] > 0);
    }
    meta[16 + TSTEPS] = off;
  }
}

// block-aggregated fill: LDS histogram -> one global atomic per (block,t) -> place.
// writes packed per-bucket edge data (src, dst, weight) for coalesced consumers.
__global__ void k_fill(const int* __restrict__ et, const int* __restrict__ src,
                       const int* __restrict__ dst, const float* __restrict__ ew,
                       int* __restrict__ meta, int* __restrict__ ssrc,
                       int* __restrict__ sdst, float* __restrict__ sew) {
  __shared__ int cnt[TSTEPS], base[TSTEPS], cur[TSTEPS];
  int tid = threadIdx.x;
  if (tid < TSTEPS) { cnt[tid] = 0; cur[tid] = 0; }
  __syncthreads();
  int e = blockIdx.x * blockDim.x + tid;
  int t = -1;
  if (e < E_EDGES) { t = et[e]; atomicAdd(&cnt[t], 1); }
  __syncthreads();
  if (tid < TSTEPS && cnt[tid]) base[tid] = atomicAdd(&meta[24 + tid], cnt[tid]);
  __syncthreads();
  if (e < E_EDGES) {
    int p = atomicAdd(&cur[t], 1);
    int pos = meta[16 + t] + base[t] + p;
    ssrc[pos] = src[e];
    sdst[pos] = dst[e];
    sew[pos] = ew[e];
  }
}

// ---------------- zero float4 region ----------------
__global__ void k_zero(float4* __restrict__ p, long n4) {
  long i = (long)blockIdx.x * blockDim.x + threadIdx.x;
  if (i < n4) p[i] = make_float4(0.f, 0.f, 0.f, 0.f);
}

// ---------------- touched flags for time-t edges (bucketed, coalesced) ----------------
__global__ void k_touch(const int* __restrict__ ssrc, const int* __restrict__ sdst,
                        const int* __restrict__ meta, int* __restrict__ touched, int t) {
  int lo = meta[16 + t], n = meta[17 + t] - meta[16 + t];
  for (int i = blockIdx.x * blockDim.x + threadIdx.x; i < n;
       i += gridDim.x * blockDim.x) {
    touched[ssrc[lo + i]] = 1;
    touched[sdst[lo + i]] = 1;
  }
}

// ---------------- LSTM part 1: g0 = x@Wih^T + b, g1 = x@(Wih+Whh)^T + b ----------------
__global__ void k_lstm_g(const float* __restrict__ hx, const float* __restrict__ Wih,
                         const float* __restrict__ Whh, const float* __restrict__ bih,
                         const float* __restrict__ bhh, float* __restrict__ g0,
                         float* __restrict__ g1) {
  int i = blockIdx.x >> 9;          // layer
  int c = blockIdx.x & 511;         // gate column 0..511
  int r = threadIdx.x;              // 0..127
  __shared__ float wi[DIM], wh[DIM];
  wi[r] = Wih[((long)i * 4 * DIM + c) * DIM + r];
  wh[r] = Whh[((long)i * 4 * DIM + c) * DIM + r];
  __syncthreads();
  const float* x = hx + ((long)i * DIM + r) * DIM;
  float a = 0.f, b = 0.f;
#pragma unroll 8
  for (int k = 0; k < DIM; ++k) {
    a = fmaf(x[k], wi[k], a);
    b = fmaf(x[k], wh[k], b);
  }
  float base = bih[i * 4 * DIM + c] + bhh[i * 4 * DIM + c];
  long o = ((long)i * 4 * DIM + c) * DIM + r;
  g0[o] = a + base;
  g1[o] = a + b + base;
}

// ---------------- LSTM part 2: gate nonlinearities + select ----------------
__global__ void k_lstm_upd(float* __restrict__ hx, float* __restrict__ cx,
                           const float* __restrict__ g0, const float* __restrict__ g1,
                           const int* __restrict__ meta, int t) {
  int idx = blockIdx.x * blockDim.x + threadIdx.x;
  if (idx >= LLAYERS * DIM * DIM) return;
  int i = idx >> 14;
  int rem = idx & 16383;
  int r = rem >> 7, j = rem & 127;
  long gb = (long)i * 4 * DIM * DIM;
  float gi0 = g0[gb + (0 * DIM + j) * DIM + r];
  float gg0 = g0[gb + (2 * DIM + j) * DIM + r];
  float go0 = g0[gb + (3 * DIM + j) * DIM + r];
  float gi1 = g1[gb + (0 * DIM + j) * DIM + r];
  float gf1 = g1[gb + (1 * DIM + j) * DIM + r];
  float gg1 = g1[gb + (2 * DIM + j) * DIM + r];
  float go1 = g1[gb + (3 * DIM + j) * DIM + r];
  float c_zero = sigm(gi0) * tanhf(gg0);
  float h_zero = sigm(go0) * tanhf(c_zero);
  float c0v = cx[idx];
  float c_st = sigm(gf1) * c0v + sigm(gi1) * tanhf(gg1);
  float h_st = sigm(go1) * tanhf(c_st);
  int first = meta[8 + t];
  int has = meta[t] > 0;
  float hold = hx[idx];
  float hi_v = first ? h_st : h_zero;
  float ci_v = first ? c0v : c_zero;
  hx[idx] = has ? hi_v : hold;
  cx[idx] = has ? ci_v : c0v;
}

// ---------------- weight prep: fp32 [K][128] -> bf16 [kb][c][g-swizzled][8] ----------------
__global__ void k_prep(const float* __restrict__ W, short* __restrict__ Wt, int K) {
  int idx = blockIdx.x * blockDim.x + threadIdx.x;
  int total = (K >> 6) * DIM * 8;
  if (idx >= total) return;
  int g = idx & 7;
  int c = (idx >> 3) & 127;
  int kb = idx >> 10;
  s16x8 s;
#pragma unroll
  for (int j = 0; j < 8; ++j) s[j] = f2bf(W[(long)(kb * 64 + g * 8 + j) * DIM + c]);
  *(s16x8*)&Wt[(((long)kb * DIM + c) * 8 + (g ^ (c & 7))) * 8] = s;
}

// ---------------- edge scatter (bucketed, coalesced): S[dst] += w * H[src] ----------------
__global__ void k_scatter(const int* __restrict__ ssrc, const int* __restrict__ sdst,
                          const float* __restrict__ sew, const int* __restrict__ meta,
                          const float* __restrict__ H, float* __restrict__ S, int t) {
  int lo = meta[16 + t];
  long n32 = (long)(meta[17 + t] - lo) << 5;
  for (long idx = (long)blockIdx.x * blockDim.x + threadIdx.x; idx < n32;
       idx += (long)gridDim.x * blockDim.x) {
    int i = (int)(idx >> 5) + lo;
    int d = ((int)idx & 31) << 2;
    float w = sew[i];
    const float4 hv = *reinterpret_cast<const float4*>(H + (long)ssrc[i] * DIM + d);
    float* o = S + (long)sdst[i] * DIM + d;
    atomicAdd(o + 0, hv.x * w);
    atomicAdd(o + 1, hv.y * w);
    atomicAdd(o + 2, hv.z * w);
    atomicAdd(o + 3, hv.w * w);
  }
}

// ---------------- MFMA GEMM: C[n][c] = act(sum_k A[row(n)][k] * W[k][c] (+bias)) ----
template <int KTILES, bool GATHER, bool RELU, bool BIAS>
__global__ __launch_bounds__(256) void k_gemm_mfma(const float* __restrict__ A,
                                                   const int* __restrict__ rowids,
                                                   const short* __restrict__ Wt,
                                                   const float* __restrict__ bias,
                                                   float* __restrict__ C, int N) {
  __shared__ short As[128 * 64];
  __shared__ short Ws[128 * 64];
  __shared__ int rid[128];
  const int tid = threadIdx.x;
  const int n0 = blockIdx.x * 128;
  if (GATHER) {
    if (tid < 128) {
      int n = n0 + tid;
      rid[tid] = (n < N) ? rowids[n] * (KTILES * 64) : 0;
    }
  }
  const int lane = tid & 63;
  const int w = tid >> 6;
  f32x4 acc[2][8] = {};
  for (int kt = 0; kt < KTILES; ++kt) {
    __syncthreads();  // rid ready (kt=0) / previous compute done
    // stage A tile: 128 rows x 64 k, fp32 -> bf16, swizzled
#pragma unroll
    for (int p = 0; p < 4; ++p) {
      int gi = p * 256 + tid;
      int row = gi >> 3, g = gi & 7;
      int n = n0 + row;
      float4 v0 = make_float4(0.f, 0.f, 0.f, 0.f), v1 = v0;
      if (n < N) {
        long base = GATHER ? (long)rid[row] : (long)n * (KTILES * 64);
        const float* ap = A + base + kt * 64 + g * 8;
        v0 = *reinterpret_cast<const float4*>(ap);
        v1 = *reinterpret_cast<const float4*>(ap + 4);
      }
      s16x8 s;
      s[0] = f2bf(v0.x); s[1] = f2bf(v0.y); s[2] = f2bf(v0.z); s[3] = f2bf(v0.w);
      s[4] = f2bf(v1.x); s[5] = f2bf(v1.y); s[6] = f2bf(v1.z); s[7] = f2bf(v1.w);
      *(s16x8*)&As[(row * 8 + (g ^ (row & 7))) * 8] = s;
    }
    // stage W chunk: pre-swizzled bf16, linear 16KB copy
    const int4* wg = reinterpret_cast<const int4*>(Wt + kt * 128 * 64);
    int4* wl = reinterpret_cast<int4*>(Ws);
#pragma unroll
    for (int p = 0; p < 4; ++p) wl[p * 256 + tid] = wg[p * 256 + tid];
    __syncthreads();
    // compute: 2 k-steps of 32, 2 row-frags x 8 col-frags
#pragma unroll
    for (int kk = 0; kk < 2; ++kk) {
      int gb = kk * 4 + (lane >> 4);
      s16x8 a[2];
#pragma unroll
      for (int fr = 0; fr < 2; ++fr) {
        int row = w * 32 + fr * 16 + (lane & 15);
        a[fr] = *(const s16x8*)&As[(row * 8 + (gb ^ (row & 7))) * 8];
      }
#pragma unroll
      for (int fc = 0; fc < 8; ++fc) {
        int col = fc * 16 + (lane & 15);
        s16x8 b = *(const s16x8*)&Ws[(col * 8 + (gb ^ (col & 7))) * 8];
        acc[0][fc] = __builtin_amdgcn_mfma_f32_16x16x32_bf16(a[0], b, acc[0][fc], 0, 0, 0);
        acc[1][fc] = __builtin_amdgcn_mfma_f32_16x16x32_bf16(a[1], b, acc[1][fc], 0, 0, 0);
      }
    }
  }
  // epilogue: C/D layout col=lane&15, row=(lane>>4)*4+reg  [m89-verified]
  const int cb = lane & 15;
  const int rb = w * 32 + (lane >> 4) * 4;
#pragma unroll
  for (int fr = 0; fr < 2; ++fr) {
#pragma unroll
    for (int reg = 0; reg < 4; ++reg) {
      int n = n0 + rb + fr * 16 + reg;
      if (n >= N) continue;
      float* cp = C + (long)n * DIM;
#pragma unroll
      for (int fc = 0; fc < 8; ++fc) {
        float x = acc[fr][fc][reg];
        if (BIAS) x += bias[fc * 16 + cb];
        if (RELU) x = fmaxf(x, 0.f);
        cp[fc * 16 + cb] = x;
      }
    }
  }
}

// ---------------- write back touched rows: h[n] = ht[n] ----------------
__global__ void k_writeback(float* __restrict__ h, const float* __restrict__ ht,
                            const int* __restrict__ touched) {
  int idx = blockIdx.x * blockDim.x + threadIdx.x;
  int n = idx >> 5;
  if (n >= N_NODES) return;
  if (!touched[n]) return;
  int d = (idx & 31) << 2;
  *reinterpret_cast<float4*>(h + (long)n * DIM + d) =
      *reinterpret_cast<const float4*>(ht + (long)n * DIM + d);
}

// ---------------- segment max (graph_id sorted) ----------------
__global__ void k_segmax(const float* __restrict__ h, const int* __restrict__ gid,
                         unsigned* __restrict__ keys) {
  int d = threadIdx.x;  // 0..127
  int n0 = blockIdx.x * 64;
  int end = min(n0 + 64, N_NODES);
  if (n0 >= N_NODES) return;
  int curg = gid[n0];
  float m = -INFINITY;
  for (int n = n0; n < end; ++n) {
    int g = gid[n];
    if (g != curg) {
      atomicMax(&keys[(long)curg * DIM + d], fenc(m));
      curg = g;
      m = -INFINITY;
    }
    m = fmaxf(m, h[(long)n * DIM + d]);
  }
  atomicMax(&keys[(long)curg * DIM + d], fenc(m));
}

// ---------------- final: logits, probs, BCE loss ----------------
__global__ void k_final(const unsigned* __restrict__ keys, const float* __restrict__ outW,
                        const float* __restrict__ outB, const float* __restrict__ y,
                        float* __restrict__ out) {
  __shared__ float lt[BGRAPH];
  int tid = threadIdx.x;  // 64 threads: 4 per graph
  int b = tid >> 2, l4 = tid & 3;
  float s = 0.f;
  for (int d = l4; d < DIM; d += 4) {
    float v = fdec(keys[(long)b * DIM + d]);
    if (!isfinite(v)) v = 0.f;
    s += v * outW[d];
  }
  s += __shfl_down(s, 1);
  s += __shfl_down(s, 2);
  if (l4 == 0) {
    float l = s + outB[0];
    out[1 + b] = 1.f / (1.f + expf(-l));
    lt[b] = fmaxf(l, 0.f) - l * y[b] + log1pf(expf(-fabsf(l)));
  }
  __syncthreads();
  if (tid == 0) {
    float acc = 0.f;
    for (int i = 0; i < BGRAPH; ++i) acc += lt[i];
    out[0] = acc / (float)BGRAPH;
  }
}

extern "C" void kernel_launch(void* const* d_in, const int* in_sizes, int n_in,
                              void* d_out, int out_size, void* d_ws, size_t ws_size,
                              hipStream_t stream) {
  const int* word_ids = (const int*)d_in[0];
  const int* src = (const int*)d_in[1];
  const int* dst = (const int*)d_in[2];
  const int* et = (const int*)d_in[3];
  const float* ew = (const float*)d_in[4];
  const int* gid = (const int*)d_in[5];
  const float* y = (const float*)d_in[6];
  const float* wemb = (const float*)d_in[7];
  const float* adW = (const float*)d_in[8];
  const float* adb = (const float*)d_in[9];
  const float* gcn = (const float*)d_in[10];
  const float* Wih = (const float*)d_in[11];
  const float* Whh = (const float*)d_in[12];
  const float* bih = (const float*)d_in[13];
  const float* bhh = (const float*)d_in[14];
  const float* outW = (const float*)d_in[15];
  const float* outB = (const float*)d_in[16];
  float* out = (float*)d_out;

  char* ws = (char*)d_ws;
  const long ND = (long)N_NODES * DIM;  // 7,680,000 floats
  float* h = (float*)ws;        ws += ND * 4;
  float* tA = (float*)ws;       ws += ND * 4;
  float* S = (float*)ws;        ws += ND * 4;
  int* touched = (int*)ws;      ws += (long)N_NODES * 4;  // contiguous after S
  float* hx = (float*)ws;       ws += LLAYERS * DIM * DIM * 4;
  float* cx = (float*)ws;       ws += LLAYERS * DIM * DIM * 4;
  float* g0 = (float*)ws;       ws += LLAYERS * 4 * DIM * DIM * 4;
  float* g1 = (float*)ws;       ws += LLAYERS * 4 * DIM * DIM * 4;
  int* meta = (int*)ws;         ws += 32 * 4;
  unsigned* keys = (unsigned*)ws; ws += BGRAPH * DIM * 4;
  int* ssrc = (int*)ws;         ws += (long)E_EDGES * 4;
  int* sdst = (int*)ws;         ws += (long)E_EDGES * 4;
  float* sew = (float*)ws;      ws += (long)E_EDGES * 4;
  short* WtAd = (short*)ws;     ws += 4L * DIM * 64 * 2;   // 256-K adapt, 64KB
  short* WtL0 = (short*)ws;     ws += 2L * DIM * 64 * 2;   // 32KB
  short* WtL1 = (short*)ws;     ws += 2L * DIM * 64 * 2;   // 32KB

  const long n4_S = ND / 4;
  const long n4_S_touch = (ND * 4 + (long)N_NODES * 4) / 16;
  const int gemm_blocks = (N_NODES + 127) / 128;

  k_init<<<128, 256, 0, stream>>>(gcn, hx, cx, meta, keys);
  k_count<<<(E_EDGES + 255) / 256, 256, 0, stream>>>(et, meta);
  k_scan<<<1, 64, 0, stream>>>(meta);
  k_fill<<<(E_EDGES + 255) / 256, 256, 0, stream>>>(et, src, dst, ew, meta,
                                                    ssrc, sdst, sew);
  k_prep<<<16, 256, 0, stream>>>(adW, WtAd, NINPK);

  // h0 = word_embeds[word_ids] @ adapt_W + adapt_b
  k_gemm_mfma<4, true, false, true><<<gemm_blocks, 256, 0, stream>>>(
      wemb, word_ids, WtAd, adb, h, N_NODES);

  for (int t = 0; t < TSTEPS; ++t) {
    k_zero<<<(int)((n4_S_touch + 255) / 256), 256, 0, stream>>>((float4*)S, n4_S_touch);
    k_touch<<<512, 256, 0, stream>>>(ssrc, sdst, meta, touched, t);
    // LSTM weight evolution
    k_lstm_g<<<LLAYERS * 512, 128, 0, stream>>>(hx, Wih, Whh, bih, bhh, g0, g1);
    k_lstm_upd<<<128, 256, 0, stream>>>(hx, cx, g0, g1, meta, t);
    k_prep<<<8, 256, 0, stream>>>(hx, WtL0, DIM);
    k_prep<<<8, 256, 0, stream>>>(hx + DIM * DIM, WtL1, DIM);
    // GCN layer 0
    k_scatter<<<4096, 256, 0, stream>>>(ssrc, sdst, sew, meta, h, S, t);
    k_gemm_mfma<2, false, true, false><<<gemm_blocks, 256, 0, stream>>>(
        S, nullptr, WtL0, nullptr, tA, N_NODES);
    // GCN layer 1
    k_zero<<<(int)((n4_S + 255) / 256), 256, 0, stream>>>((float4*)S, n4_S);
    k_scatter<<<4096, 256, 0, stream>>>(ssrc, sdst, sew, meta, tA, S, t);
    k_gemm_mfma<2, false, true, false><<<gemm_blocks, 256, 0, stream>>>(
        S, nullptr, WtL1, nullptr, tA, N_NODES);
    // write back touched rows
    k_writeback<<<N_NODES * 32 / 256, 256, 0, stream>>>(h, tA, touched);
  }

  k_segmax<<<(N_NODES + 63) / 64, 128, 0, stream>>>(h, gid, keys);
  k_final<<<1, 64, 0, stream>>>(keys, outW, outB, y, out);
}